// Round 10
// baseline (432.716 us; speedup 1.0000x reference)
//
#include <hip/hip_runtime.h>
#include <stdint.h>

typedef unsigned long long ull;
typedef unsigned int u32;
typedef __attribute__((ext_vector_type(8))) short bf16x8;
typedef __attribute__((ext_vector_type(4))) float f32x4;

// sizes: b=64, f=4, v=256, d=16384, ITERS=10; d-words = 256
//
// ws layout (bytes):
//   in_bits [64][256] ull        @ 0         (131072)
//   est0    [64][4][256] ull     @ 131072    (524288)
//   est1    [64][4][256] ull     @ 655360    (524288)
//   cbw     [4][256][256] ull    @ 1179648   (2097152)  [f][w][v]: bit l = sign cb[f][v][w*64+l]
//   cbT     [4][4][16384] ull    @ 3276800   (2097152)  [f][j][d]: bit l = sign cb[f][j*64+l][d]
//   simAB   [4][16384] u32       @ 5373952   (262144)   mode0: frag-order (sh|sl<<16); mode1: linear q16
//   bar     [256] ull            @ 5636096   (2048)     per-block barrier flags (monotonic tags)
//
// bit = 1 <=> value == -1; product of bipolars = XOR.
// signed split: sim = 16384-2h = 256*sh + sl (sh in [-64,64], sl in [0,255], both bf16-exact)
// est bit = ( sum_v sim[v]*cb[v,d] < 0 )
// Cross-XCD data (est*, simAB, bar) via AGENT-scope relaxed atomics (proven r9: absmax 0).

#define AS __HIP_MEMORY_SCOPE_AGENT
__device__ __forceinline__ ull ald(const ull* p) {
    return __hip_atomic_load(p, __ATOMIC_RELAXED, AS);
}
__device__ __forceinline__ void ast(ull* p, ull v) {
    __hip_atomic_store(p, v, __ATOMIC_RELAXED, AS);
}
__device__ __forceinline__ void ast32(u32* p, u32 v) {
    __hip_atomic_store(p, v, __ATOMIC_RELAXED, AS);
}

// ---- setup: pack input + init_estimates + codebook in ONE dispatch, 16 words/wave ----
__global__ __launch_bounds__(1024) void pack_mega(
        const float* __restrict__ in, const float* __restrict__ est_f,
        const float* __restrict__ cb,
        ull* __restrict__ in_bits, ull* __restrict__ est_bits, ull* __restrict__ cbw,
        ull* __restrict__ bar) {
    if (blockIdx.x == 0 && threadIdx.x < 256) bar[threadIdx.x] = 0;  // re-zero flags every launch
    int wid  = (int)((blockIdx.x * 1024 + threadIdx.x) >> 6);   // 21504 waves
    int lane = threadIdx.x & 63;
    int w0 = wid * 16;
    const float* s;
    int wloc;
    if (w0 < 16384)      { s = in;    wloc = w0; }
    else if (w0 < 81920) { s = est_f; wloc = w0 - 16384; }
    else                 { s = cb;    wloc = w0 - 81920; }
    ull ball[16];
    #pragma unroll
    for (int k = 0; k < 16; ++k) {
        float x = s[(size_t)(wloc + k) * 64 + lane];
        ball[k] = __ballot(x < 0.0f);
    }
    if (lane == 0) {
        if (w0 < 16384) {
            #pragma unroll
            for (int k = 0; k < 16; ++k) in_bits[wloc + k] = ball[k];
        } else if (w0 < 81920) {
            #pragma unroll
            for (int k = 0; k < 16; ++k) est_bits[wloc + k] = ball[k];
        } else {
            #pragma unroll
            for (int k = 0; k < 16; ++k) {
                int g = wloc + k;             // (f*256+v)*256 + w
                int f = g >> 16, v = (g >> 8) & 255, w = g & 255;
                cbw[(size_t)(f * 256 + w) * 256 + v] = ball[k];
            }
        }
    }
}

__global__ __launch_bounds__(1024) void pack_cbT(const ull* __restrict__ cbw, ull* __restrict__ cbT) {
    int wid  = (int)((blockIdx.x * 1024 + threadIdx.x) >> 6);   // 16384 waves
    int lane = threadIdx.x & 63;
    int f = wid >> 12, j = (wid >> 10) & 3, w = (wid >> 2) & 255, s2 = wid & 3;
    ull cw = cbw[(size_t)(f * 256 + w) * 256 + j * 64 + lane];
    ull ball[16];
    #pragma unroll
    for (int k = 0; k < 16; ++k)
        ball[k] = __ballot((cw >> (s2 * 16 + k)) & 1ull);
    if (lane == 0) {
        #pragma unroll
        for (int k = 0; k < 16; ++k)
            cbT[(size_t)(f * 4 + j) * 16384 + w * 64 + s2 * 16 + k] = ball[k];
    }
}

// ONE persistent kernel, 256 blocks x 1024 threads, 1 block/CU (146KB LDS).
// Codebook bits resident in LDS for the whole kernel; zero per-iteration re-staging.
__global__ __launch_bounds__(1024) void reso_kernel(
        const ull* __restrict__ in_bits, ull* __restrict__ est0, ull* __restrict__ est1,
        const ull* __restrict__ cbw, const ull* __restrict__ cbT,
        u32* __restrict__ simAB, ull* __restrict__ bar, float* __restrict__ out) {
    __shared__ __align__(16) char smraw[149504];
    ull*   s_cw   = (ull*)smraw;                    // [16384] swizzled granules (128KB)
    ull*   s_bT   = (ull*)(smraw + 131072);         // [4][256] raw cbT bits (8KB)
    short* s_p    = (short*)(smraw + 139264);       // [4][16][64] partial hammings (8KB)
    ull*   s_ball = (ull*)(smraw + 147456);         // [16][4][4] ballots (2KB)

    int t = threadIdx.x, lane = t & 63, wave = t >> 6;
    int bid = blockIdx.x;
    int f    = (bid & 7) >> 1;                      // XCD-swizzled: each XCD owns one f
    int sub  = (bid & 1) * 32 + (bid >> 3);         // 0..63
    int vblk = sub & 3, bblk = sub >> 2;            // A-role
    int dblk = sub;                                 // B-role

    // ---- prologue: stage codebook bits ONCE (never touched again) ----
    #pragma unroll 4
    for (int i = 0; i < 16; ++i) {
        int idx = i * 1024 + t;
        int v = idx & 63, w = idx >> 6;
        // swizzled granule: g = v*128 + (wp ^ (v&7)), wp = w>>1; conflict-free b128 reads
        s_cw[(v * 128 + ((w >> 1) ^ (v & 7))) * 2 + (w & 1)] =
            cbw[(size_t)(f * 256 + w) * 256 + vblk * 64 + v];
    }
    s_bT[t] = cbT[((size_t)f * 4 + (t >> 8)) * 16384 + dblk * 256 + (t & 255)];
    __syncthreads();

    int tag = 0;
    for (int itr = 0; itr <= 10; ++itr) {
        ull* estIn  = (itr & 1) ? est1 : est0;
        ull* estOut = (itr & 1) ? est0 : est1;
        const bool mode1 = (itr == 10);

        // ================= phase A: popcount sim (ne in registers, readlane broadcast) =====
        // lane l holds ne[bi = l>>4][w = wave*16 + (l&15)]
        {
            int bA = bblk * 4 + (lane >> 4);
            int wA = wave * 16 + (lane & 15);
            ull e0 = ald(&estIn[(size_t)(bA * 4 + 0) * 256 + wA]);
            ull e1 = ald(&estIn[(size_t)(bA * 4 + 1) * 256 + wA]);
            ull e2 = ald(&estIn[(size_t)(bA * 4 + 2) * 256 + wA]);
            ull e3 = ald(&estIn[(size_t)(bA * 4 + 3) * 256 + wA]);
            ull ef = (f == 0) ? e0 : ((f == 1) ? e1 : ((f == 2) ? e2 : e3));
            ull ne = mode1 ? ef : (in_bits[(size_t)bA * 256 + wA] ^ e0 ^ e1 ^ e2 ^ e3 ^ ef);
            u32 ne_lo = (u32)ne, ne_hi = (u32)(ne >> 32);

            int acc0 = 0, acc1 = 0, acc2 = 0, acc3 = 0;
            #pragma unroll
            for (int it = 0; it < 8; ++it) {
                int wp = wave * 8 + it;
                const ulonglong2 cw =
                    *(const ulonglong2*)&s_cw[(lane * 128 + (wp ^ (lane & 7))) * 2];
                u32 cxl = (u32)cw.x, cxh = (u32)(cw.x >> 32);
                u32 cyl = (u32)cw.y, cyh = (u32)(cw.y >> 32);
                #pragma unroll
                for (int bi = 0; bi < 4; ++bi) {
                    const int s0 = bi * 16 + it * 2;
                    u32 a0 = __builtin_amdgcn_readlane(ne_lo, s0);
                    u32 a1 = __builtin_amdgcn_readlane(ne_hi, s0);
                    u32 b0 = __builtin_amdgcn_readlane(ne_lo, s0 + 1);
                    u32 b1 = __builtin_amdgcn_readlane(ne_hi, s0 + 1);
                    int p = __builtin_popcount(cxl ^ a0) + __builtin_popcount(cxh ^ a1)
                          + __builtin_popcount(cyl ^ b0) + __builtin_popcount(cyh ^ b1);
                    if (bi == 0) acc0 += p; else if (bi == 1) acc1 += p;
                    else if (bi == 2) acc2 += p; else acc3 += p;
                }
            }
            s_p[(0 * 16 + wave) * 64 + lane] = (short)acc0;
            s_p[(1 * 16 + wave) * 64 + lane] = (short)acc1;
            s_p[(2 * 16 + wave) * 64 + lane] = (short)acc2;
            s_p[(3 * 16 + wave) * 64 + lane] = (short)acc3;
        }
        __syncthreads();
        if (t < 256) {
            int bi = t >> 6, v2 = t & 63;
            int h = 0;
            #pragma unroll
            for (int q = 0; q < 16; ++q) h += s_p[(bi * 16 + q) * 64 + v2];
            int b = bblk * 4 + bi, v = vblk * 64 + v2;
            if (!mode1) {
                int sim = 16384 - 2 * h;                  // [-16384, 16384]
                int sh = sim >> 8, sl = sim & 255;        // sim = 256*sh + sl exactly
                u32 val = (u32)(__float_as_uint((float)sh) >> 16)
                        | ((u32)(__float_as_uint((float)sl) >> 16) << 16);
                // fragment-order store: ull_idx = ((mw*8+kc)*4+n)*64 + kgrp*16 + brow
                int mw = b >> 4, brow = b & 15;
                int kc = v >> 5, kgrp = (v >> 3) & 3, j = v & 7;
                int uidx = ((((mw * 8 + kc) * 4 + (j >> 1)) * 64) + kgrp * 16 + brow) * 2 + (j & 1);
                ast32(&simAB[f * 16384 + uidx], val);
            } else {
                ast32(&simAB[((f * 64 + b) << 8) + v], (u32)(16384 - h));   // linear q16
            }
        }
        // ---- barrier (flag-array, monotonic tag) ----
        __syncthreads();                                   // drains vmcnt: stores MALL-visible
        ++tag;
        if (t == 0) ast(&bar[bid], (ull)tag);
        if (t < 256) { while (ald(&bar[t]) < (ull)tag) __builtin_amdgcn_s_sleep(1); }
        __syncthreads();
        if (mode1) break;

        // ================= phase B: est = sign(GEMM) via MFMA (B unpacked in registers) ====
        {
            int mw = wave & 3, qtr = wave >> 2;
            const ull* ab8 = (const ull*)simAB + (size_t)f * 8192;
            bf16x8 Ahi[8], Alo[8];
            #pragma unroll
            for (int kc = 0; kc < 8; ++kc) {
                union { u32 u[4]; bf16x8 v; } H, L;
                #pragma unroll
                for (int n = 0; n < 4; ++n) {
                    ull w = ald(ab8 + (((mw * 8 + kc) * 4 + n) * 64) + lane);  // coalesced 512B
                    H.u[n] = (u32)(w & 0xFFFFull) | (((u32)(w >> 32) & 0xFFFFu) << 16);
                    L.u[n] = ((u32)(w >> 16) & 0xFFFFu) | ((u32)(w >> 48) << 16);
                }
                Ahi[kc] = H.v; Alo[kc] = L.v;
            }
            #pragma unroll
            for (int ntl = 0; ntl < 4; ++ntl) {
                int nt = qtr * 4 + ntl;
                f32x4 acch = {0.f, 0.f, 0.f, 0.f}, accl = {0.f, 0.f, 0.f, 0.f};
                #pragma unroll
                for (int kc = 0; kc < 8; ++kc) {
                    ull w = s_bT[(kc >> 1) * 256 + nt * 16 + (lane & 15)];
                    u32 bits = (u32)(w >> ((kc & 1) * 32 + (lane >> 4) * 8)) & 0xFFu;
                    union { u32 u[4]; bf16x8 v; } B;
                    B.u[0] = 0x3F803F80 | ((bits & 1u) << 15)        | ((bits & 2u) << 30);
                    B.u[1] = 0x3F803F80 | (((bits >> 2) & 1u) << 15) | (((bits >> 2) & 2u) << 30);
                    B.u[2] = 0x3F803F80 | (((bits >> 4) & 1u) << 15) | (((bits >> 4) & 2u) << 30);
                    B.u[3] = 0x3F803F80 | (((bits >> 6) & 1u) << 15) | (((bits >> 6) & 2u) << 30);
                    acch = __builtin_amdgcn_mfma_f32_16x16x32_bf16(Ahi[kc], B.v, acch, 0, 0, 0);
                    accl = __builtin_amdgcn_mfma_f32_16x16x32_bf16(Alo[kc], B.v, accl, 0, 0, 0);
                }
                #pragma unroll
                for (int r = 0; r < 4; ++r) {
                    float S = 256.0f * acch[r] + accl[r];   // exact int, |S| < 2^23
                    ull m = __ballot(S < 0.0f);
                    if (lane == 0) s_ball[(wave * 4 + ntl) * 4 + r] = m;
                }
            }
        }
        __syncthreads();
        if (t < 256) {
            int b = t >> 2, w4 = t & 3;
            int wv = (w4 << 2) | (b >> 4);                  // wave that computed (mw=b>>4, qtr=w4)
            ull word = 0;
            #pragma unroll
            for (int k = 0; k < 4; ++k) {
                ull m = s_ball[(wv * 4 + k) * 4 + (b & 3)];
                word |= ((m >> (((b >> 2) & 3) * 16)) & 0xFFFFull) << (k * 16);
            }
            ast(&estOut[((size_t)(b * 4 + f)) * 256 + dblk * 4 + w4], word);
        }
        __syncthreads();                                    // drains vmcnt
        ++tag;
        if (t == 0) ast(&bar[bid], (ull)tag);
        if (t < 256) { while (ald(&bar[t]) < (ull)tag) __builtin_amdgcn_s_sleep(1); }
        __syncthreads();
    }

    // ================= final: argmax|sim| + unpack est =================
    if (t < 64) {
        int b2 = bid >> 2, f2 = bid & 3;
        const ull* sf = (const ull*)(simAB + ((size_t)(f2 * 64 + b2) << 8)) + t * 2;
        ull w0 = ald(sf), w1 = ald(sf + 1);
        int qv[4] = { (int)(u32)w0, (int)(u32)(w0 >> 32),
                      (int)(u32)w1, (int)(u32)(w1 >> 32) };
        int best_a = -1, best_v = 0;
        #pragma unroll
        for (int k = 0; k < 4; ++k) {
            int sim = 2 * qv[k] - 16384;
            int a = sim < 0 ? -sim : sim;
            if (a > best_a) { best_a = a; best_v = t * 4 + k; }   // strict > keeps first index
        }
        #pragma unroll
        for (int off = 1; off < 64; off <<= 1) {
            int oa = __shfl_xor(best_a, off);
            int ov = __shfl_xor(best_v, off);
            if (oa > best_a || (oa == best_a && ov < best_v)) { best_a = oa; best_v = ov; }
        }
        if (t == 0) out[4194304 + b2 * 4 + f2] = (float)best_v;
    }
    {   // unpack est0 -> +-1.0f: block bid covers words bid*256..+256 (matches (b2,f2) slice)
        ull w = ald(&est0[bid * 256 + (t >> 2)]);
        u32 bits = (u32)(w >> ((t & 3) * 16)) & 0xFFFFu;
        int base = bid * 16384 + (t >> 2) * 64 + (t & 3) * 16;
        #pragma unroll
        for (int j = 0; j < 4; ++j) {
            float4 o;
            o.x = ((bits >> (j * 4 + 0)) & 1u) ? -1.0f : 1.0f;
            o.y = ((bits >> (j * 4 + 1)) & 1u) ? -1.0f : 1.0f;
            o.z = ((bits >> (j * 4 + 2)) & 1u) ? -1.0f : 1.0f;
            o.w = ((bits >> (j * 4 + 3)) & 1u) ? -1.0f : 1.0f;
            *(float4*)(out + base + j * 4) = o;
        }
    }
}

extern "C" void kernel_launch(void* const* d_in, const int* in_sizes, int n_in,
                              void* d_out, int out_size, void* d_ws, size_t ws_size,
                              hipStream_t stream) {
    const float* input    = (const float*)d_in[0];
    const float* init_est = (const float*)d_in[1];
    const float* cb       = (const float*)d_in[2];
    float* out = (float*)d_out;
    char* ws = (char*)d_ws;

    ull* in_bits = (ull*)(ws + 0);
    ull* est0    = (ull*)(ws + 131072);
    ull* est1    = (ull*)(ws + 655360);
    ull* cbw     = (ull*)(ws + 1179648);
    ull* cbT     = (ull*)(ws + 3276800);
    u32* simAB   = (u32*)(ws + 5373952);
    ull* bar     = (ull*)(ws + 5636096);

    pack_mega<<<1344, 1024, 0, stream>>>(input, init_est, cb, in_bits, est0, cbw, bar);
    pack_cbT<<<1024, 1024, 0, stream>>>(cbw, cbT);

    void* kargs[] = {
        (void*)&in_bits, (void*)&est0, (void*)&est1, (void*)&cbw, (void*)&cbT,
        (void*)&simAB, (void*)&bar, (void*)&out
    };
    hipLaunchCooperativeKernel(reinterpret_cast<void*>(reso_kernel),
                               dim3(256, 1, 1), dim3(1024, 1, 1), kargs, 0, stream);
}

// Round 11
// 314.274 us; speedup vs baseline: 1.3769x; 1.3769x over previous
//
#include <hip/hip_runtime.h>
#include <stdint.h>

typedef unsigned long long ull;
typedef unsigned int u32;
typedef unsigned short ushort_t;
typedef __attribute__((ext_vector_type(8))) short bf16x8;
typedef __attribute__((ext_vector_type(4))) float f32x4;

// sizes: b=64, f=4, v=256, d=16384, ITERS=10; d-words = 256
//
// ws layout (bytes):
//   in_bits [64][256] ull        @ 0         (131072)
//   est0    [64][4][256] ull     @ 131072    (524288)
//   est1    [64][4][256] ull     @ 655360    (524288)
//   cbw     [4][256][256] ull    @ 1179648   (2097152)  [f][w][v]: bit l = sign cb[f][v][w*64+l]
//   cbT     [4][4][16384] ull    @ 3276800   (2097152)  [f][j][d]: bit l = sign cb[f][j*64+l][d]
//   simAB   [4][16384] u32       @ 5373952   (262144)   mode0: frag-order (sh|sl<<16); mode1: linear q16
//
// bit = 1 <=> value == -1; product of bipolars = XOR.
// signed split: sim = 16384-2h = 256*sh + sl (sh in [-64,64], sl in [0,255], both bf16-exact)
// est bit = ( sum_v sim[v]*cb[v,d] < 0 )

// ---- setup: pack input + init_estimates + codebook in ONE dispatch, 16 words/wave ----
__global__ __launch_bounds__(1024) void pack_mega(
        const float* __restrict__ in, const float* __restrict__ est_f,
        const float* __restrict__ cb,
        ull* __restrict__ in_bits, ull* __restrict__ est_bits, ull* __restrict__ cbw) {
    int wid  = (int)((blockIdx.x * 1024 + threadIdx.x) >> 6);   // 21504 waves
    int lane = threadIdx.x & 63;
    int w0 = wid * 16;
    const float* s;
    int wloc;
    if (w0 < 16384)      { s = in;    wloc = w0; }
    else if (w0 < 81920) { s = est_f; wloc = w0 - 16384; }
    else                 { s = cb;    wloc = w0 - 81920; }
    ull ball[16];
    #pragma unroll
    for (int k = 0; k < 16; ++k) {
        float x = s[(size_t)(wloc + k) * 64 + lane];
        ball[k] = __ballot(x < 0.0f);
    }
    if (lane == 0) {
        if (w0 < 16384) {
            #pragma unroll
            for (int k = 0; k < 16; ++k) in_bits[wloc + k] = ball[k];
        } else if (w0 < 81920) {
            #pragma unroll
            for (int k = 0; k < 16; ++k) est_bits[wloc + k] = ball[k];
        } else {
            #pragma unroll
            for (int k = 0; k < 16; ++k) {
                int g = wloc + k;             // (f*256+v)*256 + w
                int f = g >> 16, v = (g >> 8) & 255, w = g & 255;
                cbw[(size_t)(f * 256 + w) * 256 + v] = ball[k];
            }
        }
    }
}

__global__ __launch_bounds__(1024) void pack_cbT(const ull* __restrict__ cbw, ull* __restrict__ cbT) {
    int wid  = (int)((blockIdx.x * 1024 + threadIdx.x) >> 6);   // 16384 waves
    int lane = threadIdx.x & 63;
    int f = wid >> 12, j = (wid >> 10) & 3, w = (wid >> 2) & 255, s2 = wid & 3;
    ull cw = cbw[(size_t)(f * 256 + w) * 256 + j * 64 + lane];
    ull ball[16];
    #pragma unroll
    for (int k = 0; k < 16; ++k)
        ball[k] = __ballot((cw >> (s2 * 16 + k)) & 1ull);
    if (lane == 0) {
        #pragma unroll
        for (int k = 0; k < 16; ++k)
            cbT[(size_t)(f * 4 + j) * 16384 + w * 64 + s2 * 16 + k] = ball[k];
    }
}

// phase A v4: codebook words straight to VGPRs (no LDS staging), ne per-lane + readlane bcast.
// grid 256 x 1024; block = XCD-swizzled (f, vblk of 64 v, bblk of 4 b).
// thread (wave,lane): owns v = vblk*64+lane, w-range wave*16..+15; holds ne for (bi=lane>>4, w=wave*16+(lane&15)).
// mode 0: frag-order (sh|sl<<16) to simAB.  mode 1: ne = est_f, linear raw q16.
__global__ __launch_bounds__(1024) void simA4_kernel(
        const ull* __restrict__ in_bits, const ull* __restrict__ est_in,
        const ull* __restrict__ cbw, u32* __restrict__ simAB, int mode) {
    __shared__ short s_p[4][16][64];              // 8KB [bi][wave][v-local]
    int t = threadIdx.x, lane = t & 63, wave = t >> 6;
    int bid = blockIdx.x;
    int f    = (bid & 7) >> 1;
    int sub  = (bid & 1) * 32 + (bid >> 3);       // 0..63
    int vblk = sub & 3, bblk = sub >> 2;

    // ne word for this lane's (bi, w)
    int bA = bblk * 4 + (lane >> 4);
    int wA = wave * 16 + (lane & 15);
    ull e0 = est_in[(size_t)(bA * 4 + 0) * 256 + wA];
    ull e1 = est_in[(size_t)(bA * 4 + 1) * 256 + wA];
    ull e2 = est_in[(size_t)(bA * 4 + 2) * 256 + wA];
    ull e3 = est_in[(size_t)(bA * 4 + 3) * 256 + wA];
    ull ef = (f == 0) ? e0 : ((f == 1) ? e1 : ((f == 2) ? e2 : e3));
    ull ne = mode ? ef : (in_bits[(size_t)bA * 256 + wA] ^ e0 ^ e1 ^ e2 ^ e3 ^ ef);
    u32 ne_lo = (u32)ne, ne_hi = (u32)(ne >> 32);

    // cw words straight to VGPRs: cw[k] = cbw[f][wave*16+k][vblk*64+lane]  (512B-coalesced)
    ull cw[16];
    const ull* cbase = cbw + (size_t)(f * 256 + wave * 16) * 256 + vblk * 64 + lane;
    #pragma unroll
    for (int k = 0; k < 16; ++k) cw[k] = cbase[(size_t)k * 256];

    int acc0 = 0, acc1 = 0, acc2 = 0, acc3 = 0;
    #pragma unroll
    for (int k = 0; k < 16; ++k) {
        u32 cl = (u32)cw[k], ch = (u32)(cw[k] >> 32);
        #pragma unroll
        for (int bi = 0; bi < 4; ++bi) {
            u32 a0 = __builtin_amdgcn_readlane(ne_lo, bi * 16 + k);
            u32 a1 = __builtin_amdgcn_readlane(ne_hi, bi * 16 + k);
            int p = __builtin_popcount(cl ^ a0) + __builtin_popcount(ch ^ a1);
            if (bi == 0) acc0 += p; else if (bi == 1) acc1 += p;
            else if (bi == 2) acc2 += p; else acc3 += p;
        }
    }
    s_p[0][wave][lane] = (short)acc0;
    s_p[1][wave][lane] = (short)acc1;
    s_p[2][wave][lane] = (short)acc2;
    s_p[3][wave][lane] = (short)acc3;
    __syncthreads();

    if (t < 256) {
        int bi = t >> 6, v2 = t & 63;
        int h = 0;
        #pragma unroll
        for (int q = 0; q < 16; ++q) h += s_p[bi][q][v2];
        int b = bblk * 4 + bi, v = vblk * 64 + v2;
        if (!mode) {
            int sim = 16384 - 2 * h;                  // [-16384, 16384]
            int sh = sim >> 8, sl = sim & 255;        // sim = 256*sh + sl exactly
            u32 val = (u32)(__float_as_uint((float)sh) >> 16)
                    | ((u32)(__float_as_uint((float)sl) >> 16) << 16);
            // fragment-order store (verified r10): v = kc*32 + kgrp*8 + j
            int mw = b >> 4, brow = b & 15;
            int kc = v >> 5, kgrp = (v >> 3) & 3, j = v & 7;
            int uidx = ((((mw * 8 + kc) * 4 + (j >> 1)) * 64) + kgrp * 16 + brow) * 2 + (j & 1);
            simAB[f * 16384 + uidx] = val;
        } else {
            simAB[((f * 64 + b) << 8) + v] = (u32)(16384 - h);   // linear q16
        }
    }
}

// phase B v4: one block per (f, dblk) [XCD-swizzled], 512 threads (8 waves).
// B-frags unpacked bits->bf16 in registers from 8KB s_bT; A-frags coalesced from frag-order simAB.
__global__ __launch_bounds__(512) void gemm4_kernel(
        const ull* __restrict__ cbT, const u32* __restrict__ simAB,
        ull* __restrict__ est_out) {
    int bid = blockIdx.x;
    int fB   = (bid & 7) >> 1;
    int dblk = (bid & 1) * 32 + (bid >> 3);       // 0..63
    __shared__ ull s_bT[1024];                    // 8KB  [j][256 d-local]
    __shared__ ull s_ball[8][8][4];               // 2KB  [wave][ntl][r]
    int t = threadIdx.x, lane = t & 63, wave = t >> 6;

    s_bT[t]       = cbT[((size_t)fB * 4 + (t >> 8)) * 16384 + dblk * 256 + (t & 255)];
    s_bT[t + 512] = cbT[((size_t)fB * 4 + ((t + 512) >> 8)) * 16384 + dblk * 256 + (t & 255)];

    // A-frags: coalesced 512B loads from frag-ordered simAB (verified r10)
    int mw = wave & 3, ntb = (wave >> 2) << 3;
    const ull* ab8 = (const ull*)simAB + (size_t)fB * 8192;
    bf16x8 Ahi[8], Alo[8];
    #pragma unroll
    for (int kc = 0; kc < 8; ++kc) {
        union { u32 u[4]; bf16x8 v; } H, L;
        #pragma unroll
        for (int n = 0; n < 4; ++n) {
            ull w = ab8[(((mw * 8 + kc) * 4 + n) * 64) + lane];
            H.u[n] = (u32)(w & 0xFFFFull) | (((u32)(w >> 32) & 0xFFFFu) << 16);
            L.u[n] = ((u32)(w >> 16) & 0xFFFFu) | ((u32)(w >> 48) << 16);
        }
        Ahi[kc] = H.v; Alo[kc] = L.v;
    }
    __syncthreads();

    #pragma unroll 2
    for (int ntl = 0; ntl < 8; ++ntl) {
        int nt = ntb + ntl;
        f32x4 acch = {0.f, 0.f, 0.f, 0.f}, accl = {0.f, 0.f, 0.f, 0.f};
        #pragma unroll
        for (int kc = 0; kc < 8; ++kc) {
            ull w = s_bT[(kc >> 1) * 256 + nt * 16 + (lane & 15)];
            u32 bits = (u32)(w >> ((kc & 1) * 32 + (lane >> 4) * 8)) & 0xFFu;
            union { u32 u[4]; bf16x8 v; } B;
            B.u[0] = 0x3F803F80 | ((bits & 1u) << 15)        | ((bits & 2u) << 30);
            B.u[1] = 0x3F803F80 | (((bits >> 2) & 1u) << 15) | (((bits >> 2) & 2u) << 30);
            B.u[2] = 0x3F803F80 | (((bits >> 4) & 1u) << 15) | (((bits >> 4) & 2u) << 30);
            B.u[3] = 0x3F803F80 | (((bits >> 6) & 1u) << 15) | (((bits >> 6) & 2u) << 30);
            acch = __builtin_amdgcn_mfma_f32_16x16x32_bf16(Ahi[kc], B.v, acch, 0, 0, 0);
            accl = __builtin_amdgcn_mfma_f32_16x16x32_bf16(Alo[kc], B.v, accl, 0, 0, 0);
        }
        #pragma unroll
        for (int r = 0; r < 4; ++r) {
            float S = 256.0f * acch[r] + accl[r];   // exact int, |S| < 2^23
            // C-frag row m = mw*16 + (lane>>4)*4 + r, col d-local = lane&15
            ull m = __ballot(S < 0.0f);
            if (lane == 0) s_ball[wave][ntl][r] = m;
        }
    }
    __syncthreads();

    if (t < 256) {
        int b = t >> 2, w4 = t & 3;                 // est word (b, d-word dblk*4+w4)
        int wv = (b >> 4) + ((w4 >= 2) ? 4 : 0);    // writer wave for (mw=b>>4, nt-half)
        ull word = 0;
        #pragma unroll
        for (int k = 0; k < 4; ++k) {
            int nt = w4 * 4 + k;
            ull m = s_ball[wv][nt & 7][b & 3];
            word |= ((m >> (((b >> 2) & 3) * 16)) & 0xFFFFull) << (k * 16);
        }
        est_out[((size_t)(b * 4 + fB)) * 256 + dblk * 4 + w4] = word;
    }
}

// final: argmax|2q-16384| per (b,f) from simF (blocks 0..255) + unpack est -> +-1.0f
__global__ __launch_bounds__(256) void final2_kernel(
        const ull* __restrict__ est, const u32* __restrict__ simF,
        float* __restrict__ out) {
    int t = threadIdx.x;
    if (blockIdx.x < 256 && t < 64) {
        int b = blockIdx.x >> 2, f = blockIdx.x & 3;
        const u32* sf = simF + ((size_t)(f * 64 + b) << 8) + t * 4;
        int best_a = -1, best_v = 0;
        #pragma unroll
        for (int k = 0; k < 4; ++k) {
            int sim = 2 * (int)sf[k] - 16384;
            int a = sim < 0 ? -sim : sim;
            if (a > best_a) { best_a = a; best_v = t * 4 + k; }  // strict > keeps first index
        }
        #pragma unroll
        for (int off = 1; off < 64; off <<= 1) {
            int oa = __shfl_xor(best_a, off);
            int ov = __shfl_xor(best_v, off);
            if (oa > best_a || (oa == best_a && ov < best_v)) { best_a = oa; best_v = ov; }
        }
        if (t == 0) out[4194304 + b * 4 + f] = (float)best_v;
    }
    // unpack: 4194304 floats over 2048 blocks -> 2048 floats/block, 8/thread
    int flat = blockIdx.x * 2048 + t * 8;
    ull w = est[flat >> 6];
    unsigned bits = (unsigned)(w >> (flat & 63)) & 0xFFu;
    float4 lo, hi;
    lo.x = (bits & 1u)   ? -1.0f : 1.0f;
    lo.y = (bits & 2u)   ? -1.0f : 1.0f;
    lo.z = (bits & 4u)   ? -1.0f : 1.0f;
    lo.w = (bits & 8u)   ? -1.0f : 1.0f;
    hi.x = (bits & 16u)  ? -1.0f : 1.0f;
    hi.y = (bits & 32u)  ? -1.0f : 1.0f;
    hi.z = (bits & 64u)  ? -1.0f : 1.0f;
    hi.w = (bits & 128u) ? -1.0f : 1.0f;
    *(float4*)(out + flat)     = lo;
    *(float4*)(out + flat + 4) = hi;
}

extern "C" void kernel_launch(void* const* d_in, const int* in_sizes, int n_in,
                              void* d_out, int out_size, void* d_ws, size_t ws_size,
                              hipStream_t stream) {
    const float* input    = (const float*)d_in[0];
    const float* init_est = (const float*)d_in[1];
    const float* cb       = (const float*)d_in[2];
    float* out = (float*)d_out;
    char* ws = (char*)d_ws;

    ull* in_bits = (ull*)(ws + 0);
    ull* est0    = (ull*)(ws + 131072);
    ull* est1    = (ull*)(ws + 655360);
    ull* cbw     = (ull*)(ws + 1179648);
    ull* cbT     = (ull*)(ws + 3276800);
    u32* simAB   = (u32*)(ws + 5373952);

    pack_mega<<<1344, 1024, 0, stream>>>(input, init_est, cb, in_bits, est0, cbw);
    pack_cbT<<<1024, 1024, 0, stream>>>(cbw, cbT);

    ull* bufs[2] = { est0, est1 };
    for (int i = 0; i < 10; ++i) {
        simA4_kernel<<<256, 1024, 0, stream>>>(in_bits, bufs[i & 1], cbw, simAB, 0);
        gemm4_kernel<<<256, 512, 0, stream>>>(cbT, simAB, bufs[(i & 1) ^ 1]);
    }
    // final est in est0: raw sim(est,cb) then argmax+unpack
    simA4_kernel<<<256, 1024, 0, stream>>>(in_bits, est0, cbw, simAB, 1);
    final2_kernel<<<2048, 256, 0, stream>>>(est0, simAB, out);
}